// Round 6
// baseline (325.796 us; speedup 1.0000x reference)
//
#include <hip/hip_runtime.h>
#include <hip/hip_bf16.h>
#include <math.h>

#define T_ 8
#define N_ 2048
#define F_ 128
#define H_ 4
#define NT_ (N_ / 32)     // 64 key tiles per (h,t)
#define SPLIT_ 3          // key-split factor (flash-decoding)
#define NPART_ (H_ * T_ * 16 * SPLIT_)   // 1536 partials

typedef unsigned int u32;
typedef unsigned short ushort_t;
typedef float f32x16 __attribute__((ext_vector_type(16)));
typedef _Float16 f16x8 __attribute__((ext_vector_type(8)));
typedef u32 u32x4 __attribute__((ext_vector_type(4)));

// ---------------------------------------------------------------------------
// Kernel 1: th = x @ W per (h,t) in fp32; writes fp16 hi (all t), fp16 lo
// residual (t == T-1 only, for Q), and transposed hi copy th_hiT[ht][n/32][g][32].
// ---------------------------------------------------------------------------
__global__ __launch_bounds__(256) void k_th(const float* __restrict__ x,
                                            const float* __restrict__ W,
                                            ushort_t* __restrict__ th_hi,
                                            ushort_t* __restrict__ th_qlo,
                                            ushort_t* __restrict__ th_hiT) {
    __shared__ float xs[64][132];

    const int b = blockIdx.x;
    const int h = b / (T_ * (N_ / 64));
    const int rem = b % (T_ * (N_ / 64));
    const int t = rem / (N_ / 64);
    const int n0 = (rem % (N_ / 64)) * 64;
    const int tid = threadIdx.x;

    {
        const int r = tid >> 2;
        const int c0 = (tid & 3) * 32;
        const float4* src = reinterpret_cast<const float4*>(
            x + ((size_t)t * N_ + (n0 + r)) * F_ + c0);
        #pragma unroll
        for (int u = 0; u < 8; ++u) {
            float4 v = src[u];
            int c = c0 + u * 4;
            xs[r][c + 0] = v.x; xs[r][c + 1] = v.y;
            xs[r][c + 2] = v.z; xs[r][c + 3] = v.w;
        }
    }
    __syncthreads();

    const int rowg = tid >> 4;
    const int colg = tid & 15;
    const int r0 = rowg * 4;
    const int c0 = colg * 8;

    float acc[4][8];
    #pragma unroll
    for (int i = 0; i < 4; ++i)
        #pragma unroll
        for (int j = 0; j < 8; ++j) acc[i][j] = 0.f;

    const float* Wb = W + (size_t)h * F_ * F_ + c0;
    #pragma unroll 4
    for (int f = 0; f < F_; ++f) {
        const float4 w0 = *reinterpret_cast<const float4*>(Wb + (size_t)f * F_);
        const float4 w1 = *reinterpret_cast<const float4*>(Wb + (size_t)f * F_ + 4);
        float a[4];
        #pragma unroll
        for (int i = 0; i < 4; ++i) a[i] = xs[r0 + i][f];
        #pragma unroll
        for (int i = 0; i < 4; ++i) {
            acc[i][0] += a[i] * w0.x; acc[i][1] += a[i] * w0.y;
            acc[i][2] += a[i] * w0.z; acc[i][3] += a[i] * w0.w;
            acc[i][4] += a[i] * w1.x; acc[i][5] += a[i] * w1.y;
            acc[i][6] += a[i] * w1.z; acc[i][7] += a[i] * w1.w;
        }
    }

    ushort_t hiv[4][8], lov[4][8];
    #pragma unroll
    for (int i = 0; i < 4; ++i)
        #pragma unroll
        for (int j = 0; j < 8; ++j) {
            float v = acc[i][j];
            _Float16 hh = (_Float16)v;                 // RTN
            _Float16 ll = (_Float16)(v - (float)hh);   // residual
            hiv[i][j] = __builtin_bit_cast(ushort_t, hh);
            lov[i][j] = __builtin_bit_cast(ushort_t, ll);
        }

    const size_t rowbase = (((size_t)h * T_ + t) * N_ + n0);
    #pragma unroll
    for (int i = 0; i < 4; ++i) {
        uint4 hv = *reinterpret_cast<uint4*>(&hiv[i][0]);
        *reinterpret_cast<uint4*>(th_hi + (rowbase + r0 + i) * F_ + c0) = hv;
    }
    if (t == T_ - 1) {
        #pragma unroll
        for (int i = 0; i < 4; ++i) {
            uint4 lv = *reinterpret_cast<uint4*>(&lov[i][0]);
            *reinterpret_cast<uint4*>(th_qlo + ((size_t)h * N_ + n0 + r0 + i) * F_ + c0) = lv;
        }
    }

    // transposed chunked hi copy: [h][t][nc][g][32]
    {
        const int nc = (n0 + r0) >> 5;
        const int nin = r0 & 31;
        ushort_t* base = th_hiT + ((((size_t)h * T_ + t) * (N_ / 32) + nc) * F_) * 32;
        #pragma unroll
        for (int j = 0; j < 8; ++j) {
            u32 p0 = (u32)hiv[0][j] | ((u32)hiv[1][j] << 16);
            u32 p1 = (u32)hiv[2][j] | ((u32)hiv[3][j] << 16);
            u32* dst = reinterpret_cast<u32*>(base + (size_t)(c0 + j) * 32 + nin);
            dst[0] = p0;
            dst[1] = p1;
        }
    }
}

// ---------------------------------------------------------------------------
// Kernel 2: MFMA flash attention, key-split x3 (flash-decoding).
// grid = 1536 = (h,t,qtile,split); block = 256 (4 waves x 32 q-cols).
// Each block handles 22/22/20 key-tiles; partial written as normalized
// o (fp16) + (m,l) f32; merged in k_out.
// (Bisect round: permlane32_swap asm reverted to proven __shfl_xor forms.)
// ---------------------------------------------------------------------------
__global__ __launch_bounds__(256, 3) void k_attn(const ushort_t* __restrict__ th_hi,
                                                 const ushort_t* __restrict__ th_qlo,
                                                 const ushort_t* __restrict__ th_hiT,
                                                 ushort_t* __restrict__ o_norm,
                                                 float* __restrict__ ml) {
    __shared__ ushort_t kh[3][32][128];
    __shared__ ushort_t vt[3][64][72];

    const int tid = threadIdx.x;
    const int lane = tid & 63;
    const int w = tid >> 6;
    const int l31 = lane & 31;
    const int h5 = lane >> 5;

    // XCD-grouping swizzle: 192 blocks per XCD = 4 complete (h,t) groups
    const int vid = (blockIdx.x & 7) * 192 + (blockIdx.x >> 3);
    const int grp = vid / 48;            // h*8 + t
    const int within = vid % 48;
    const int qt = within / 3;
    const int sp = within % 3;
    const int h = grp >> 3;
    const int t = grp & 7;
    const int q0 = qt * 128 + w * 32;
    const int base_mt = sp * 22;
    const int ntiles = (sp == 2) ? 20 : 22;
    const int pidx = (grp * 16 + qt) * 3 + sp;

    const size_t ht = (size_t)h * T_ + t;
    const ushort_t* Khi_g = th_hi + ht * (N_ * F_);
    const ushort_t* VT_g  = th_hiT + ht * ((N_ / 32) * F_ * 32);
    const ushort_t* Qhi_g = th_hi + ((size_t)h * T_ + (T_ - 1)) * (N_ * F_);
    const ushort_t* Qlo_g = th_qlo + (size_t)h * (N_ * F_);

    // Q fragments: lane -> q = q0+l31, f = ks*16 + h5*8 + j
    f16x8 qh[8], ql[8];
    {
        const ushort_t* qrh = Qhi_g + (size_t)(q0 + l31) * F_ + h5 * 8;
        const ushort_t* qrl = Qlo_g + (size_t)(q0 + l31) * F_ + h5 * 8;
        #pragma unroll
        for (int ks = 0; ks < 8; ++ks) {
            qh[ks] = *reinterpret_cast<const f16x8*>(qrh + ks * 16);
            ql[ks] = *reinterpret_cast<const f16x8*>(qrl + ks * 16);
        }
    }

    const int sm = tid >> 3;            // K staging row 0..31
    const int sfc = tid & 7;            // K staging 16-elem f chunk
    const int ssx = sm & 15;
    const int sg = tid >> 1;            // V staging g-row 0..127
    const int smh = (tid & 1) * 16;     // V staging m half

    f32x16 o2[4];
    #pragma unroll
    for (int gs = 0; gs < 4; ++gs)
        #pragma unroll
        for (int r = 0; r < 16; ++r) o2[gs][r] = 0.f;

    float m_run = -3e38f, l_run = 0.f;
    const float CL2 = 1.4426950408889634f;

    uint4 sa0, sa1, sv0, sv1;   // T14 staging registers

    auto stage_load = [&](int mt) {
        const size_t grow = (size_t)((base_mt + mt) * 32 + sm) * F_ + sfc * 16;
        sa0 = *reinterpret_cast<const uint4*>(Khi_g + grow);
        sa1 = *reinterpret_cast<const uint4*>(Khi_g + grow + 8);
        const ushort_t* vsrc = VT_g + (size_t)(base_mt + mt) * (F_ * 32) + (size_t)sg * 32 + smh;
        sv0 = *reinterpret_cast<const uint4*>(vsrc);
        sv1 = *reinterpret_cast<const uint4*>(vsrc + 8);
    };
    auto stage_write = [&](int buf) {
        *reinterpret_cast<uint4*>(&kh[buf][sm][((sfc * 2 + 0) ^ ssx) * 8]) = sa0;
        *reinterpret_cast<uint4*>(&kh[buf][sm][((sfc * 2 + 1) ^ ssx) * 8]) = sa1;
        ushort_t* vdst = &vt[buf][sg >> 1][(sg & 1) * 32 + smh];
        *reinterpret_cast<uint4*>(vdst) = sv0;
        *reinterpret_cast<uint4*>(vdst + 8) = sv1;
    };
    auto scores = [&](int buf) -> f32x16 {
        f32x16 S;
        #pragma unroll
        for (int r = 0; r < 16; ++r) S[r] = 0.f;
        __builtin_amdgcn_s_setprio(1);
        #pragma unroll
        for (int ks = 0; ks < 8; ++ks) {
            const f16x8 ah = *reinterpret_cast<const f16x8*>(
                &kh[buf][l31][((ks * 2 + h5) ^ (l31 & 15)) * 8]);
            S = __builtin_amdgcn_mfma_f32_32x32x16_f16(ah, qh[ks], S, 0, 0, 0);
            S = __builtin_amdgcn_mfma_f32_32x32x16_f16(ah, ql[ks], S, 0, 0, 0);
        }
        __builtin_amdgcn_s_setprio(0);
        return S;
    };
    auto softmax_pv = [&](f32x16& S, int buf) {
        // row-max tree (per-lane q column) + half-wave combine (shfl_xor, proven)
        float a0 = fmaxf(S[0], S[1]),  a1 = fmaxf(S[2], S[3]);
        float a2 = fmaxf(S[4], S[5]),  a3 = fmaxf(S[6], S[7]);
        float a4 = fmaxf(S[8], S[9]),  a5 = fmaxf(S[10], S[11]);
        float a6 = fmaxf(S[12], S[13]), a7 = fmaxf(S[14], S[15]);
        float b0 = fmaxf(a0, a1), b1 = fmaxf(a2, a3);
        float b2 = fmaxf(a4, a5), b3 = fmaxf(a6, a7);
        float tm = fmaxf(fmaxf(b0, b1), fmaxf(b2, b3));
        tm = fmaxf(tm, __shfl_xor(tm, 32));

        // T13: defer rescale unless max grew beyond threshold
        if (__any(tm > m_run + 8.f)) {
            const float Mn = fmaxf(m_run, tm);
            const float alpha = exp2f((m_run - Mn) * CL2);
            l_run *= alpha;
            #pragma unroll
            for (int gs = 0; gs < 4; ++gs)
                #pragma unroll
                for (int r = 0; r < 16; ++r) o2[gs][r] *= alpha;
            m_run = Mn;
        }
        const float mc = m_run * CL2;
        float p[16];
        #pragma unroll
        for (int r = 0; r < 16; ++r) p[r] = exp2f(S[r] * CL2 - mc);
        float ts = (((p[0] + p[1]) + (p[2] + p[3])) + ((p[4] + p[5]) + (p[6] + p[7])))
                 + (((p[8] + p[9]) + (p[10] + p[11])) + ((p[12] + p[13]) + (p[14] + p[15])));
        ts += __shfl_xor(ts, 32);
        l_run += ts;

        // pack P^T fragments in-register (cvt_pkrtz + shfl_xor swap, proven R4)
        u32 pk[8], xk[8];
        #pragma unroll
        for (int c = 0; c < 8; ++c) {
            auto r2 = __builtin_amdgcn_cvt_pkrtz(p[2 * c], p[2 * c + 1]);
            pk[c] = __builtin_bit_cast(u32, r2);
        }
        #pragma unroll
        for (int c = 0; c < 8; ++c) xk[c] = (u32)__shfl_xor((int)pk[c], 32);

        u32x4 t0, t1;
        t0.x = h5 ? xk[2] : pk[0];
        t0.y = h5 ? xk[3] : pk[1];
        t0.z = h5 ? pk[2] : xk[0];
        t0.w = h5 ? pk[3] : xk[1];
        t1.x = h5 ? xk[6] : pk[4];
        t1.y = h5 ? xk[7] : pk[5];
        t1.z = h5 ? pk[6] : xk[4];
        t1.w = h5 ? pk[7] : xk[5];
        f16x8 pb0 = __builtin_bit_cast(f16x8, t0);
        f16x8 pb1 = __builtin_bit_cast(f16x8, t1);

        __builtin_amdgcn_s_setprio(1);
        #pragma unroll
        for (int gs = 0; gs < 4; ++gs) {
            const int g = gs * 32 + l31;
            const ushort_t* vrow = &vt[buf][g >> 1][(g & 1) * 32];
            f16x8 v0 = *reinterpret_cast<const f16x8*>(vrow + h5 * 8);
            f16x8 v1 = *reinterpret_cast<const f16x8*>(vrow + 16 + h5 * 8);
            o2[gs] = __builtin_amdgcn_mfma_f32_32x32x16_f16(v0, pb0, o2[gs], 0, 0, 0);
            o2[gs] = __builtin_amdgcn_mfma_f32_32x32x16_f16(v1, pb1, o2[gs], 0, 0, 0);
        }
        __builtin_amdgcn_s_setprio(0);
    };

    // prologue: stage tiles 0 and 1, compute scores(tile 0)
    stage_load(0); stage_write(0);
    stage_load(1); stage_write(1);
    __syncthreads();
    f32x16 S_A = scores(0);

    int cur = 0, nxt = 1, stg = 2;
    for (int mt = 0; mt < ntiles - 1; ++mt) {
        if (mt < ntiles - 2) stage_load(mt + 2);  // issue-early (T14)
        f32x16 S_B = scores(nxt);                 // MFMA for next tile...
        softmax_pv(S_A, cur);                     // ...overlaps softmax+PV of this one
        if (mt < ntiles - 2) stage_write(stg);    // write-late (T14)
        __syncthreads();
        S_A = S_B;
        const int tmp = cur; cur = nxt; nxt = stg; stg = tmp;
    }
    softmax_pv(S_A, cur);   // final tile

    // epilogue: write normalized fp16 partial + (m,l)
    const float inv = 1.f / l_run;
    const int qin = w * 32 + l31;
    ushort_t* obase = o_norm + (size_t)pidx * (128 * 128) + (size_t)qin * 128;
    #pragma unroll
    for (int gs = 0; gs < 4; ++gs)
        #pragma unroll
        for (int rp = 0; rp < 8; ++rp) {
            const int r = rp * 2;
            const int g = gs * 32 + (r & 3) + 8 * (r >> 2) + 4 * h5;
            _Float16 e0 = (_Float16)(o2[gs][r] * inv);
            _Float16 e1 = (_Float16)(o2[gs][r + 1] * inv);
            u32 pck = (u32)__builtin_bit_cast(ushort_t, e0) |
                      ((u32)__builtin_bit_cast(ushort_t, e1) << 16);
            *reinterpret_cast<u32*>(obase + g) = pck;
        }
    if (h5 == 0) {
        ml[(size_t)pidx * 256 + qin] = m_run;
        ml[(size_t)pidx * 256 + 128 + qin] = l_run;
    }
}

// ---------------------------------------------------------------------------
// Kernel 3: 3-way flash merge + t-sum + elu + head-mean.
// out[n,g] = mean_h elu( (1/T) * sum_t merge_s(o,m,l) )
// thread = (n, g-quad): 65536 threads = 256 blocks x 256.
// ---------------------------------------------------------------------------
__global__ __launch_bounds__(256) void k_out(const ushort_t* __restrict__ o_norm,
                                             const float* __restrict__ ml,
                                             float* __restrict__ out) {
    const int idx = blockIdx.x * blockDim.x + threadIdx.x;
    const int n = idx >> 5;
    const int g0 = (idx & 31) * 4;
    const int qt = n >> 7;
    const int qin = n & 127;
    const float CL2 = 1.4426950408889634f;

    float acc[4] = {0.f, 0.f, 0.f, 0.f};
    #pragma unroll
    for (int h = 0; h < H_; ++h) {
        float hs[4] = {0.f, 0.f, 0.f, 0.f};
        #pragma unroll
        for (int t = 0; t < T_; ++t) {
            const int grp = h * 8 + t;
            const size_t base3 = (size_t)(grp * 16 + qt) * 3;
            float m0 = ml[(base3 + 0) * 256 + qin];
            float l0 = ml[(base3 + 0) * 256 + 128 + qin];
            float m1 = ml[(base3 + 1) * 256 + qin];
            float l1 = ml[(base3 + 1) * 256 + 128 + qin];
            float m2 = ml[(base3 + 2) * 256 + qin];
            float l2 = ml[(base3 + 2) * 256 + 128 + qin];
            const float M = fmaxf(m0, fmaxf(m1, m2));
            const float w0 = l0 * exp2f((m0 - M) * CL2);
            const float w1 = l1 * exp2f((m1 - M) * CL2);
            const float w2 = l2 * exp2f((m2 - M) * CL2);
            const float invW = 1.f / (w0 + w1 + w2);
            const float c0 = w0 * invW, c1 = w1 * invW, c2 = w2 * invW;
            #pragma unroll
            for (int s = 0; s < 3; ++s) {
                const float cs = (s == 0) ? c0 : (s == 1) ? c1 : c2;
                uint2 od = *reinterpret_cast<const uint2*>(
                    o_norm + (base3 + s) * (128 * 128) + (size_t)qin * 128 + g0);
                hs[0] += cs * (float)__builtin_bit_cast(_Float16, (ushort_t)(od.x & 0xffff));
                hs[1] += cs * (float)__builtin_bit_cast(_Float16, (ushort_t)(od.x >> 16));
                hs[2] += cs * (float)__builtin_bit_cast(_Float16, (ushort_t)(od.y & 0xffff));
                hs[3] += cs * (float)__builtin_bit_cast(_Float16, (ushort_t)(od.y >> 16));
            }
        }
        #pragma unroll
        for (int k = 0; k < 4; ++k) {
            const float e = hs[k] * (1.f / (float)T_);
            acc[k] += (e > 0.f) ? e : (expf(e) - 1.f);
        }
    }
    float4 r = {acc[0] * 0.25f, acc[1] * 0.25f, acc[2] * 0.25f, acc[3] * 0.25f};
    *reinterpret_cast<float4*>(out + (size_t)n * F_ + g0) = r;
}

extern "C" void kernel_launch(void* const* d_in, const int* in_sizes, int n_in,
                              void* d_out, int out_size, void* d_ws, size_t ws_size,
                              hipStream_t stream) {
    const float* x = (const float*)d_in[0];   // (T, N, F)
    const float* W = (const float*)d_in[1];   // (H, F, F)
    float* out = (float*)d_out;               // (N, F)

    // ws layout: th_hi 16MB | th_hiT 16MB | th_qlo 2MB | o_norm 48MB | ml 1.5MB
    const size_t TH = (size_t)H_ * T_ * N_ * F_;        // 8,388,608
    const size_t QL = (size_t)H_ * N_ * F_;             // 1,048,576
    ushort_t* th_hi  = (ushort_t*)d_ws;
    ushort_t* th_hiT = th_hi + TH;
    ushort_t* th_qlo = th_hiT + TH;
    ushort_t* o_norm = th_qlo + QL;
    float* ml = (float*)(o_norm + (size_t)NPART_ * 128 * 128);

    k_th<<<H_ * T_ * (N_ / 64), 256, 0, stream>>>(x, W, th_hi, th_qlo, th_hiT);
    k_attn<<<NPART_, 256, 0, stream>>>(th_hi, th_qlo, th_hiT, o_norm, ml);
    k_out<<<(N_ * 32) / 256, 256, 0, stream>>>(o_norm, ml, out);
}

// Round 7
// 173.671 us; speedup vs baseline: 1.8759x; 1.8759x over previous
//
#include <hip/hip_runtime.h>
#include <hip/hip_bf16.h>
#include <math.h>

#define T_ 8
#define N_ 2048
#define F_ 128
#define H_ 4
#define NT_ (N_ / 32)   // 64 key tiles per (h,t)

typedef unsigned int u32;
typedef unsigned short ushort_t;
typedef float f32x16 __attribute__((ext_vector_type(16)));
typedef _Float16 f16x8 __attribute__((ext_vector_type(8)));
typedef u32 u32x4 __attribute__((ext_vector_type(4)));

// ---------------------------------------------------------------------------
// Kernel 1: th = x @ W per (h,t) in fp32; writes fp16 hi (all t), fp16 lo
// residual (t == T-1 only, for Q), and transposed hi copy th_hiT[ht][n/32][g][32].
// ---------------------------------------------------------------------------
__global__ __launch_bounds__(256) void k_th(const float* __restrict__ x,
                                            const float* __restrict__ W,
                                            ushort_t* __restrict__ th_hi,
                                            ushort_t* __restrict__ th_qlo,
                                            ushort_t* __restrict__ th_hiT) {
    __shared__ float xs[64][132];

    const int b = blockIdx.x;
    const int h = b / (T_ * (N_ / 64));
    const int rem = b % (T_ * (N_ / 64));
    const int t = rem / (N_ / 64);
    const int n0 = (rem % (N_ / 64)) * 64;
    const int tid = threadIdx.x;

    {
        const int r = tid >> 2;
        const int c0 = (tid & 3) * 32;
        const float4* src = reinterpret_cast<const float4*>(
            x + ((size_t)t * N_ + (n0 + r)) * F_ + c0);
        #pragma unroll
        for (int u = 0; u < 8; ++u) {
            float4 v = src[u];
            int c = c0 + u * 4;
            xs[r][c + 0] = v.x; xs[r][c + 1] = v.y;
            xs[r][c + 2] = v.z; xs[r][c + 3] = v.w;
        }
    }
    __syncthreads();

    const int rowg = tid >> 4;
    const int colg = tid & 15;
    const int r0 = rowg * 4;
    const int c0 = colg * 8;

    float acc[4][8];
    #pragma unroll
    for (int i = 0; i < 4; ++i)
        #pragma unroll
        for (int j = 0; j < 8; ++j) acc[i][j] = 0.f;

    const float* Wb = W + (size_t)h * F_ * F_ + c0;
    #pragma unroll 4
    for (int f = 0; f < F_; ++f) {
        const float4 w0 = *reinterpret_cast<const float4*>(Wb + (size_t)f * F_);
        const float4 w1 = *reinterpret_cast<const float4*>(Wb + (size_t)f * F_ + 4);
        float a[4];
        #pragma unroll
        for (int i = 0; i < 4; ++i) a[i] = xs[r0 + i][f];
        #pragma unroll
        for (int i = 0; i < 4; ++i) {
            acc[i][0] += a[i] * w0.x; acc[i][1] += a[i] * w0.y;
            acc[i][2] += a[i] * w0.z; acc[i][3] += a[i] * w0.w;
            acc[i][4] += a[i] * w1.x; acc[i][5] += a[i] * w1.y;
            acc[i][6] += a[i] * w1.z; acc[i][7] += a[i] * w1.w;
        }
    }

    ushort_t hiv[4][8], lov[4][8];
    #pragma unroll
    for (int i = 0; i < 4; ++i)
        #pragma unroll
        for (int j = 0; j < 8; ++j) {
            float v = acc[i][j];
            _Float16 hh = (_Float16)v;                 // RTN
            _Float16 ll = (_Float16)(v - (float)hh);   // residual
            hiv[i][j] = __builtin_bit_cast(ushort_t, hh);
            lov[i][j] = __builtin_bit_cast(ushort_t, ll);
        }

    const size_t rowbase = (((size_t)h * T_ + t) * N_ + n0);
    #pragma unroll
    for (int i = 0; i < 4; ++i) {
        uint4 hv = *reinterpret_cast<uint4*>(&hiv[i][0]);
        *reinterpret_cast<uint4*>(th_hi + (rowbase + r0 + i) * F_ + c0) = hv;
    }
    if (t == T_ - 1) {
        #pragma unroll
        for (int i = 0; i < 4; ++i) {
            uint4 lv = *reinterpret_cast<uint4*>(&lov[i][0]);
            *reinterpret_cast<uint4*>(th_qlo + ((size_t)h * N_ + n0 + r0 + i) * F_ + c0) = lv;
        }
    }

    // transposed chunked hi copy: [h][t][nc][g][32]
    {
        const int nc = (n0 + r0) >> 5;
        const int nin = r0 & 31;
        ushort_t* base = th_hiT + ((((size_t)h * T_ + t) * (N_ / 32) + nc) * F_) * 32;
        #pragma unroll
        for (int j = 0; j < 8; ++j) {
            u32 p0 = (u32)hiv[0][j] | ((u32)hiv[1][j] << 16);
            u32 p1 = (u32)hiv[2][j] | ((u32)hiv[3][j] << 16);
            u32* dst = reinterpret_cast<u32*>(base + (size_t)(c0 + j) * 32 + nin);
            dst[0] = p0;
            dst[1] = p1;
        }
    }
}

// ---------------------------------------------------------------------------
// Kernel 2: MFMA flash attention, S^T = K*Q^T, fp16 2-term hi/lo scores.
// R7: dual independent MFMA accumulator chains (S_h, S_l) halve the score
// dependency depth; stage_write hoisted before softmax; max3-friendly tree.
// grid = 512 = (h,t,qtile); block = 256 (4 waves x 32 q-cols each); 2 blk/CU.
// ---------------------------------------------------------------------------
__global__ __launch_bounds__(256, 2) void k_attn(const ushort_t* __restrict__ th_hi,
                                                 const ushort_t* __restrict__ th_qlo,
                                                 const ushort_t* __restrict__ th_hiT,
                                                 float* __restrict__ s_part) {
    __shared__ ushort_t kh[3][32][128];
    __shared__ ushort_t vt[3][64][72];

    const int tid = threadIdx.x;
    const int lane = tid & 63;
    const int w = tid >> 6;
    const int l31 = lane & 31;
    const int h5 = lane >> 5;

    // XCD-grouping swizzle (proven R4: FETCH ~20MB): 64 vids per XCD
    const int vid = ((blockIdx.x & 7) << 6) | (blockIdx.x >> 3);
    const int h = vid >> 7;
    const int t = (vid >> 4) & 7;
    const int qt = vid & 15;
    const int q0 = qt * 128 + w * 32;

    const size_t ht = (size_t)h * T_ + t;
    const ushort_t* Khi_g = th_hi + ht * (N_ * F_);
    const ushort_t* VT_g  = th_hiT + ht * ((N_ / 32) * F_ * 32);
    const ushort_t* Qhi_g = th_hi + ((size_t)h * T_ + (T_ - 1)) * (N_ * F_);
    const ushort_t* Qlo_g = th_qlo + (size_t)h * (N_ * F_);

    // Q fragments: lane -> q = q0+l31, f = ks*16 + h5*8 + j
    f16x8 qh[8], ql[8];
    {
        const ushort_t* qrh = Qhi_g + (size_t)(q0 + l31) * F_ + h5 * 8;
        const ushort_t* qrl = Qlo_g + (size_t)(q0 + l31) * F_ + h5 * 8;
        #pragma unroll
        for (int ks = 0; ks < 8; ++ks) {
            qh[ks] = *reinterpret_cast<const f16x8*>(qrh + ks * 16);
            ql[ks] = *reinterpret_cast<const f16x8*>(qrl + ks * 16);
        }
    }

    const int sm = tid >> 3;            // K staging row 0..31
    const int sfc = tid & 7;            // K staging 16-elem f chunk
    const int ssx = sm & 15;
    const int sg = tid >> 1;            // V staging g-row 0..127
    const int smh = (tid & 1) * 16;     // V staging m half

    f32x16 o2[4];
    #pragma unroll
    for (int gs = 0; gs < 4; ++gs)
        #pragma unroll
        for (int r = 0; r < 16; ++r) o2[gs][r] = 0.f;

    float m_run = -3e38f, l_run = 0.f;
    const float CL2 = 1.4426950408889634f;

    uint4 sa0, sa1, sv0, sv1;   // T14 staging registers

    auto stage_load = [&](int mt) {
        const size_t grow = (size_t)(mt * 32 + sm) * F_ + sfc * 16;
        sa0 = *reinterpret_cast<const uint4*>(Khi_g + grow);
        sa1 = *reinterpret_cast<const uint4*>(Khi_g + grow + 8);
        const ushort_t* vsrc = VT_g + (size_t)mt * (F_ * 32) + (size_t)sg * 32 + smh;
        sv0 = *reinterpret_cast<const uint4*>(vsrc);
        sv1 = *reinterpret_cast<const uint4*>(vsrc + 8);
    };
    auto stage_write = [&](int buf) {
        *reinterpret_cast<uint4*>(&kh[buf][sm][((sfc * 2 + 0) ^ ssx) * 8]) = sa0;
        *reinterpret_cast<uint4*>(&kh[buf][sm][((sfc * 2 + 1) ^ ssx) * 8]) = sa1;
        ushort_t* vdst = &vt[buf][sg >> 1][(sg & 1) * 32 + smh];
        *reinterpret_cast<uint4*>(vdst) = sv0;
        *reinterpret_cast<uint4*>(vdst + 8) = sv1;
    };
    // dual independent accumulator chains: halves MFMA dependency depth
    auto scores = [&](int buf) -> f32x16 {
        f32x16 Sh, Sl;
        #pragma unroll
        for (int r = 0; r < 16; ++r) { Sh[r] = 0.f; Sl[r] = 0.f; }
        __builtin_amdgcn_s_setprio(1);
        #pragma unroll
        for (int ks = 0; ks < 8; ++ks) {
            const f16x8 ah = *reinterpret_cast<const f16x8*>(
                &kh[buf][l31][((ks * 2 + h5) ^ (l31 & 15)) * 8]);
            Sh = __builtin_amdgcn_mfma_f32_32x32x16_f16(ah, qh[ks], Sh, 0, 0, 0);
            Sl = __builtin_amdgcn_mfma_f32_32x32x16_f16(ah, ql[ks], Sl, 0, 0, 0);
        }
        __builtin_amdgcn_s_setprio(0);
        return Sh + Sl;
    };
    auto softmax_pv = [&](f32x16& S, int buf) {
        // row-max via max3-fusable triples + half-wave combine
        float m0 = fmaxf(fmaxf(S[0], S[1]), S[2]);
        float m1 = fmaxf(fmaxf(S[3], S[4]), S[5]);
        float m2 = fmaxf(fmaxf(S[6], S[7]), S[8]);
        float m3 = fmaxf(fmaxf(S[9], S[10]), S[11]);
        float m4 = fmaxf(fmaxf(S[12], S[13]), S[14]);
        float tm = fmaxf(fmaxf(fmaxf(m0, m1), m2), fmaxf(fmaxf(m3, m4), S[15]));
        tm = fmaxf(tm, __shfl_xor(tm, 32));

        // T13: defer rescale unless max grew beyond threshold
        if (__any(tm > m_run + 8.f)) {
            const float Mn = fmaxf(m_run, tm);
            const float alpha = exp2f((m_run - Mn) * CL2);
            l_run *= alpha;
            #pragma unroll
            for (int gs = 0; gs < 4; ++gs)
                #pragma unroll
                for (int r = 0; r < 16; ++r) o2[gs][r] *= alpha;
            m_run = Mn;
        }
        const float mc = m_run * CL2;
        float p[16];
        #pragma unroll
        for (int r = 0; r < 16; ++r) p[r] = exp2f(S[r] * CL2 - mc);
        float ts = (((p[0] + p[1]) + (p[2] + p[3])) + ((p[4] + p[5]) + (p[6] + p[7])))
                 + (((p[8] + p[9]) + (p[10] + p[11])) + ((p[12] + p[13]) + (p[14] + p[15])));
        ts += __shfl_xor(ts, 32);
        l_run += ts;

        // pack P^T fragments in-register (cvt_pkrtz + shfl_xor swap, proven R4)
        u32 pk[8], xk[8];
        #pragma unroll
        for (int c = 0; c < 8; ++c) {
            auto r2 = __builtin_amdgcn_cvt_pkrtz(p[2 * c], p[2 * c + 1]);
            pk[c] = __builtin_bit_cast(u32, r2);
        }
        #pragma unroll
        for (int c = 0; c < 8; ++c) xk[c] = (u32)__shfl_xor((int)pk[c], 32);

        u32x4 t0, t1;
        t0.x = h5 ? xk[2] : pk[0];
        t0.y = h5 ? xk[3] : pk[1];
        t0.z = h5 ? pk[2] : xk[0];
        t0.w = h5 ? pk[3] : xk[1];
        t1.x = h5 ? xk[6] : pk[4];
        t1.y = h5 ? xk[7] : pk[5];
        t1.z = h5 ? pk[6] : xk[4];
        t1.w = h5 ? pk[7] : xk[5];
        f16x8 pb0 = __builtin_bit_cast(f16x8, t0);
        f16x8 pb1 = __builtin_bit_cast(f16x8, t1);

        __builtin_amdgcn_s_setprio(1);
        #pragma unroll
        for (int gs = 0; gs < 4; ++gs) {
            const int g = gs * 32 + l31;
            const ushort_t* vrow = &vt[buf][g >> 1][(g & 1) * 32];
            f16x8 v0 = *reinterpret_cast<const f16x8*>(vrow + h5 * 8);
            f16x8 v1 = *reinterpret_cast<const f16x8*>(vrow + 16 + h5 * 8);
            o2[gs] = __builtin_amdgcn_mfma_f32_32x32x16_f16(v0, pb0, o2[gs], 0, 0, 0);
            o2[gs] = __builtin_amdgcn_mfma_f32_32x32x16_f16(v1, pb1, o2[gs], 0, 0, 0);
        }
        __builtin_amdgcn_s_setprio(0);
    };

    // prologue: stage tiles 0 and 1, compute scores(tile 0)
    stage_load(0); stage_write(0);
    stage_load(1); stage_write(1);
    __syncthreads();
    f32x16 S_A = scores(0);

    int cur = 0, nxt = 1, stg = 2;
    for (int mt = 0; mt < NT_ - 1; ++mt) {
        if (mt < NT_ - 2) stage_load(mt + 2);     // issue-early (T14)
        f32x16 S_B = scores(nxt);                 // MFMA for next tile...
        if (mt < NT_ - 2) stage_write(stg);       // LDS write hidden under softmax
        softmax_pv(S_A, cur);                     // ...overlaps softmax+PV of this one
        __syncthreads();
        S_A = S_B;
        const int tmp = cur; cur = nxt; nxt = stg; stg = tmp;
    }
    softmax_pv(S_A, cur);   // final tile (buffer 63 % 3 = 0)

    // epilogue: normalize and scatter-store out^T
    const float inv = 1.f / l_run;
    float* dst = s_part + (ht * N_ + (q0 + l31)) * F_;
    #pragma unroll
    for (int gs = 0; gs < 4; ++gs)
        #pragma unroll
        for (int r = 0; r < 16; ++r) {
            const int g = gs * 32 + (r & 3) + 8 * (r >> 2) + 4 * h5;
            dst[g] = o2[gs][r] * inv;
        }
}

// ---------------------------------------------------------------------------
// Kernel 3: out[n,g] = mean_h elu( (1/T) * sum_t s_part[h][t][n][g] )
// ---------------------------------------------------------------------------
__global__ __launch_bounds__(256) void k_out(const float* __restrict__ s_part,
                                             float* __restrict__ out) {
    const int i = blockIdx.x * blockDim.x + threadIdx.x;
    if (i >= (N_ * F_) / 4) return;
    const float4* sp = reinterpret_cast<const float4*>(s_part);
    float4 acc = {0.f, 0.f, 0.f, 0.f};
    const float invT = 1.f / (float)T_;
    #pragma unroll
    for (int h = 0; h < H_; ++h) {
        float4 hs = {0.f, 0.f, 0.f, 0.f};
        #pragma unroll
        for (int t = 0; t < T_; ++t) {
            float4 v = sp[(size_t)(h * T_ + t) * (N_ * F_ / 4) + i];
            hs.x += v.x; hs.y += v.y; hs.z += v.z; hs.w += v.w;
        }
        float ex = hs.x * invT, ey = hs.y * invT, ez = hs.z * invT, ew = hs.w * invT;
        acc.x += (ex > 0.f) ? ex : (expf(ex) - 1.f);
        acc.y += (ey > 0.f) ? ey : (expf(ey) - 1.f);
        acc.z += (ez > 0.f) ? ez : (expf(ez) - 1.f);
        acc.w += (ew > 0.f) ? ew : (expf(ew) - 1.f);
    }
    const float q = 1.f / (float)H_;
    float4 r = {acc.x * q, acc.y * q, acc.z * q, acc.w * q};
    reinterpret_cast<float4*>(out)[i] = r;
}

extern "C" void kernel_launch(void* const* d_in, const int* in_sizes, int n_in,
                              void* d_out, int out_size, void* d_ws, size_t ws_size,
                              hipStream_t stream) {
    const float* x = (const float*)d_in[0];   // (T, N, F)
    const float* W = (const float*)d_in[1];   // (H, F, F)
    float* out = (float*)d_out;               // (N, F)

    // ws layout: th_hi 16MB | th_hiT 16MB | th_qlo 2MB | s_part 32MB (66MB)
    const size_t TH = (size_t)H_ * T_ * N_ * F_;        // 8,388,608
    const size_t QL = (size_t)H_ * N_ * F_;             // 1,048,576
    ushort_t* th_hi  = (ushort_t*)d_ws;
    ushort_t* th_hiT = th_hi + TH;
    ushort_t* th_qlo = th_hiT + TH;
    float* s_part = (float*)(th_qlo + QL);

    k_th<<<H_ * T_ * (N_ / 64), 256, 0, stream>>>(x, W, th_hi, th_qlo, th_hiT);
    k_attn<<<512, 256, 0, stream>>>(th_hi, th_qlo, th_hiT, s_part);
    k_out<<<(N_ * F_ / 4 + 255) / 256, 256, 0, stream>>>(s_part, out);
}

// Round 8
// 157.175 us; speedup vs baseline: 2.0728x; 1.1050x over previous
//
#include <hip/hip_runtime.h>
#include <hip/hip_bf16.h>
#include <math.h>

#define T_ 8
#define N_ 2048
#define F_ 128
#define H_ 4
#define NT_ (N_ / 32)   // 64 key tiles per (h,t)

typedef unsigned int u32;
typedef unsigned short ushort_t;
typedef float f32x16 __attribute__((ext_vector_type(16)));
typedef _Float16 f16x8 __attribute__((ext_vector_type(8)));
typedef u32 u32x4 __attribute__((ext_vector_type(4)));

// ---------------------------------------------------------------------------
// Kernel 1: th = x @ W per (h,t) in fp32; writes fp16 hi and the transposed
// copy th_hiT[ht][n/32][g][32] with the inner m-index PERMUTED (bit2<->bit3)
// so PV's B-fragment needs no cross-lane shuffles (k-permutation trick).
// ---------------------------------------------------------------------------
__global__ __launch_bounds__(256) void k_th(const float* __restrict__ x,
                                            const float* __restrict__ W,
                                            ushort_t* __restrict__ th_hi,
                                            ushort_t* __restrict__ th_hiT) {
    __shared__ float xs[64][132];

    const int b = blockIdx.x;
    const int h = b / (T_ * (N_ / 64));
    const int rem = b % (T_ * (N_ / 64));
    const int t = rem / (N_ / 64);
    const int n0 = (rem % (N_ / 64)) * 64;
    const int tid = threadIdx.x;

    {
        const int r = tid >> 2;
        const int c0 = (tid & 3) * 32;
        const float4* src = reinterpret_cast<const float4*>(
            x + ((size_t)t * N_ + (n0 + r)) * F_ + c0);
        #pragma unroll
        for (int u = 0; u < 8; ++u) {
            float4 v = src[u];
            int c = c0 + u * 4;
            xs[r][c + 0] = v.x; xs[r][c + 1] = v.y;
            xs[r][c + 2] = v.z; xs[r][c + 3] = v.w;
        }
    }
    __syncthreads();

    const int rowg = tid >> 4;
    const int colg = tid & 15;
    const int r0 = rowg * 4;
    const int c0 = colg * 8;

    float acc[4][8];
    #pragma unroll
    for (int i = 0; i < 4; ++i)
        #pragma unroll
        for (int j = 0; j < 8; ++j) acc[i][j] = 0.f;

    const float* Wb = W + (size_t)h * F_ * F_ + c0;
    #pragma unroll 4
    for (int f = 0; f < F_; ++f) {
        const float4 w0 = *reinterpret_cast<const float4*>(Wb + (size_t)f * F_);
        const float4 w1 = *reinterpret_cast<const float4*>(Wb + (size_t)f * F_ + 4);
        float a[4];
        #pragma unroll
        for (int i = 0; i < 4; ++i) a[i] = xs[r0 + i][f];
        #pragma unroll
        for (int i = 0; i < 4; ++i) {
            acc[i][0] += a[i] * w0.x; acc[i][1] += a[i] * w0.y;
            acc[i][2] += a[i] * w0.z; acc[i][3] += a[i] * w0.w;
            acc[i][4] += a[i] * w1.x; acc[i][5] += a[i] * w1.y;
            acc[i][6] += a[i] * w1.z; acc[i][7] += a[i] * w1.w;
        }
    }

    ushort_t hiv[4][8];
    #pragma unroll
    for (int i = 0; i < 4; ++i)
        #pragma unroll
        for (int j = 0; j < 8; ++j) {
            _Float16 hh = (_Float16)acc[i][j];   // RTN
            hiv[i][j] = __builtin_bit_cast(ushort_t, hh);
        }

    const size_t rowbase = (((size_t)h * T_ + t) * N_ + n0);
    #pragma unroll
    for (int i = 0; i < 4; ++i) {
        uint4 hv = *reinterpret_cast<uint4*>(&hiv[i][0]);
        *reinterpret_cast<uint4*>(th_hi + (rowbase + r0 + i) * F_ + c0) = hv;
    }

    // transposed chunked copy: [h][t][nc][g][32], inner m-index bit2<->bit3
    {
        const int nc = (n0 + r0) >> 5;
        const int nin = r0 & 31;                 // multiple of 4
        const int npin = (nin & 0x10) | ((nin & 4) << 1) | ((nin & 8) >> 1);
        ushort_t* base = th_hiT + ((((size_t)h * T_ + t) * (N_ / 32) + nc) * F_) * 32;
        #pragma unroll
        for (int j = 0; j < 8; ++j) {
            u32 p0 = (u32)hiv[0][j] | ((u32)hiv[1][j] << 16);
            u32 p1 = (u32)hiv[2][j] | ((u32)hiv[3][j] << 16);
            u32* dst = reinterpret_cast<u32*>(base + (size_t)(c0 + j) * 32 + npin);
            dst[0] = p0;
            dst[1] = p1;
        }
    }
}

// ---------------------------------------------------------------------------
// Kernel 2: MFMA flash attention, S^T = K*Q^T, single-term fp16 scores.
// R8: shuffle-free P-pack (pi-permuted V layout), deferred l-combine,
// per-tile DS ops cut from ~26 to ~17 per wave.
// grid = 512 = (h,t,qtile); block = 256 (4 waves x 32 q-cols); 2 blk/CU.
// ---------------------------------------------------------------------------
__global__ __launch_bounds__(256, 2) void k_attn(const ushort_t* __restrict__ th_hi,
                                                 const ushort_t* __restrict__ th_hiT,
                                                 float* __restrict__ s_part) {
    __shared__ ushort_t kh[3][32][128];
    __shared__ ushort_t vt[3][64][72];

    const int tid = threadIdx.x;
    const int lane = tid & 63;
    const int w = tid >> 6;
    const int l31 = lane & 31;
    const int h5 = lane >> 5;

    // XCD-grouping swizzle (proven: FETCH ~20MB): 64 vids per XCD
    const int vid = ((blockIdx.x & 7) << 6) | (blockIdx.x >> 3);
    const int h = vid >> 7;
    const int t = (vid >> 4) & 7;
    const int qt = vid & 15;
    const int q0 = qt * 128 + w * 32;

    const size_t ht = (size_t)h * T_ + t;
    const ushort_t* Khi_g = th_hi + ht * (N_ * F_);
    const ushort_t* VT_g  = th_hiT + ht * ((N_ / 32) * F_ * 32);
    const ushort_t* Qhi_g = th_hi + ((size_t)h * T_ + (T_ - 1)) * (N_ * F_);

    // Q fragments: lane -> q = q0+l31, f = ks*16 + h5*8 + j
    f16x8 qh[8];
    {
        const ushort_t* qrh = Qhi_g + (size_t)(q0 + l31) * F_ + h5 * 8;
        #pragma unroll
        for (int ks = 0; ks < 8; ++ks)
            qh[ks] = *reinterpret_cast<const f16x8*>(qrh + ks * 16);
    }

    const int sm = tid >> 3;            // K staging row 0..31
    const int sfc = tid & 7;            // K staging 16-elem f chunk
    const int ssx = sm & 15;
    const int sg = tid >> 1;            // V staging g-row 0..127
    const int smh = (tid & 1) * 16;     // V staging m half

    f32x16 o2[4];
    #pragma unroll
    for (int gs = 0; gs < 4; ++gs)
        #pragma unroll
        for (int r = 0; r < 16; ++r) o2[gs][r] = 0.f;

    float m_run = -3e38f, l_run = 0.f;  // l_run: per-half-wave PARTIAL
    const float CL2 = 1.4426950408889634f;

    uint4 sa0, sa1, sv0, sv1;   // T14 staging registers

    auto stage_load = [&](int mt) {
        const size_t grow = (size_t)(mt * 32 + sm) * F_ + sfc * 16;
        sa0 = *reinterpret_cast<const uint4*>(Khi_g + grow);
        sa1 = *reinterpret_cast<const uint4*>(Khi_g + grow + 8);
        const ushort_t* vsrc = VT_g + (size_t)mt * (F_ * 32) + (size_t)sg * 32 + smh;
        sv0 = *reinterpret_cast<const uint4*>(vsrc);
        sv1 = *reinterpret_cast<const uint4*>(vsrc + 8);
    };
    auto stage_write = [&](int buf) {
        *reinterpret_cast<uint4*>(&kh[buf][sm][((sfc * 2 + 0) ^ ssx) * 8]) = sa0;
        *reinterpret_cast<uint4*>(&kh[buf][sm][((sfc * 2 + 1) ^ ssx) * 8]) = sa1;
        ushort_t* vdst = &vt[buf][sg >> 1][(sg & 1) * 32 + smh];
        *reinterpret_cast<uint4*>(vdst) = sv0;
        *reinterpret_cast<uint4*>(vdst + 8) = sv1;
    };
    auto scores = [&](int buf) -> f32x16 {
        f32x16 S;
        #pragma unroll
        for (int r = 0; r < 16; ++r) S[r] = 0.f;
        __builtin_amdgcn_s_setprio(1);
        #pragma unroll
        for (int ks = 0; ks < 8; ++ks) {
            const f16x8 ah = *reinterpret_cast<const f16x8*>(
                &kh[buf][l31][((ks * 2 + h5) ^ (l31 & 15)) * 8]);
            S = __builtin_amdgcn_mfma_f32_32x32x16_f16(ah, qh[ks], S, 0, 0, 0);
        }
        __builtin_amdgcn_s_setprio(0);
        return S;
    };
    auto softmax_pv = [&](f32x16& S, int buf) {
        // row-max tree + half-wave combine (the only per-tile shuffle)
        float m0 = fmaxf(fmaxf(S[0], S[1]), S[2]);
        float m1 = fmaxf(fmaxf(S[3], S[4]), S[5]);
        float m2 = fmaxf(fmaxf(S[6], S[7]), S[8]);
        float m3 = fmaxf(fmaxf(S[9], S[10]), S[11]);
        float m4 = fmaxf(fmaxf(S[12], S[13]), S[14]);
        float tm = fmaxf(fmaxf(fmaxf(m0, m1), m2), fmaxf(fmaxf(m3, m4), S[15]));
        tm = fmaxf(tm, __shfl_xor(tm, 32));

        // T13: defer rescale unless max grew beyond threshold
        if (__any(tm > m_run + 8.f)) {
            const float Mn = fmaxf(m_run, tm);
            const float alpha = exp2f((m_run - Mn) * CL2);
            l_run *= alpha;
            #pragma unroll
            for (int gs = 0; gs < 4; ++gs)
                #pragma unroll
                for (int r = 0; r < 16; ++r) o2[gs][r] *= alpha;
            m_run = Mn;
        }
        const float mc = m_run * CL2;
        float p[16];
        #pragma unroll
        for (int r = 0; r < 16; ++r) p[r] = exp2f(S[r] * CL2 - mc);
        float ts = (((p[0] + p[1]) + (p[2] + p[3])) + ((p[4] + p[5]) + (p[6] + p[7])))
                 + (((p[8] + p[9]) + (p[10] + p[11])) + ((p[12] + p[13]) + (p[14] + p[15])));
        l_run += ts;   // per-half partial; combined once in epilogue

        // shuffle-free P^T fragments: pi-permuted V makes pb = p directly
        u32 pk[8];
        #pragma unroll
        for (int c = 0; c < 8; ++c) {
            auto r2 = __builtin_amdgcn_cvt_pkrtz(p[2 * c], p[2 * c + 1]);
            pk[c] = __builtin_bit_cast(u32, r2);
        }
        u32x4 t0, t1;
        t0.x = pk[0]; t0.y = pk[1]; t0.z = pk[2]; t0.w = pk[3];
        t1.x = pk[4]; t1.y = pk[5]; t1.z = pk[6]; t1.w = pk[7];
        f16x8 pb0 = __builtin_bit_cast(f16x8, t0);
        f16x8 pb1 = __builtin_bit_cast(f16x8, t1);

        __builtin_amdgcn_s_setprio(1);
        #pragma unroll
        for (int gs = 0; gs < 4; ++gs) {
            const int g = gs * 32 + l31;
            const ushort_t* vrow = &vt[buf][g >> 1][(g & 1) * 32];
            f16x8 v0 = *reinterpret_cast<const f16x8*>(vrow + h5 * 8);
            f16x8 v1 = *reinterpret_cast<const f16x8*>(vrow + 16 + h5 * 8);
            o2[gs] = __builtin_amdgcn_mfma_f32_32x32x16_f16(v0, pb0, o2[gs], 0, 0, 0);
            o2[gs] = __builtin_amdgcn_mfma_f32_32x32x16_f16(v1, pb1, o2[gs], 0, 0, 0);
        }
        __builtin_amdgcn_s_setprio(0);
    };

    // prologue: stage tiles 0 and 1, compute scores(tile 0)
    stage_load(0); stage_write(0);
    stage_load(1); stage_write(1);
    __syncthreads();
    f32x16 S_A = scores(0);

    int cur = 0, nxt = 1, stg = 2;
    for (int mt = 0; mt < NT_ - 1; ++mt) {
        if (mt < NT_ - 2) stage_load(mt + 2);     // issue-early (T14)
        f32x16 S_B = scores(nxt);                 // MFMA for next tile...
        if (mt < NT_ - 2) stage_write(stg);       // LDS write hidden under softmax
        softmax_pv(S_A, cur);                     // ...overlaps softmax+PV of this one
        __syncthreads();
        S_A = S_B;
        const int tmp = cur; cur = nxt; nxt = stg; stg = tmp;
    }
    softmax_pv(S_A, cur);   // final tile (buffer 63 % 3 = 0)

    // epilogue: combine l halves, normalize, scatter-store out^T
    const float l_tot = l_run + __shfl_xor(l_run, 32);
    const float inv = 1.f / l_tot;
    float* dst = s_part + (ht * N_ + (q0 + l31)) * F_;
    #pragma unroll
    for (int gs = 0; gs < 4; ++gs)
        #pragma unroll
        for (int r = 0; r < 16; ++r) {
            const int g = gs * 32 + (r & 3) + 8 * (r >> 2) + 4 * h5;
            dst[g] = o2[gs][r] * inv;
        }
}

// ---------------------------------------------------------------------------
// Kernel 3: out[n,g] = mean_h elu( (1/T) * sum_t s_part[h][t][n][g] )
// ---------------------------------------------------------------------------
__global__ __launch_bounds__(256) void k_out(const float* __restrict__ s_part,
                                             float* __restrict__ out) {
    const int i = blockIdx.x * blockDim.x + threadIdx.x;
    if (i >= (N_ * F_) / 4) return;
    const float4* sp = reinterpret_cast<const float4*>(s_part);
    float4 acc = {0.f, 0.f, 0.f, 0.f};
    const float invT = 1.f / (float)T_;
    #pragma unroll
    for (int h = 0; h < H_; ++h) {
        float4 hs = {0.f, 0.f, 0.f, 0.f};
        #pragma unroll
        for (int t = 0; t < T_; ++t) {
            float4 v = sp[(size_t)(h * T_ + t) * (N_ * F_ / 4) + i];
            hs.x += v.x; hs.y += v.y; hs.z += v.z; hs.w += v.w;
        }
        float ex = hs.x * invT, ey = hs.y * invT, ez = hs.z * invT, ew = hs.w * invT;
        acc.x += (ex > 0.f) ? ex : (expf(ex) - 1.f);
        acc.y += (ey > 0.f) ? ey : (expf(ey) - 1.f);
        acc.z += (ez > 0.f) ? ez : (expf(ez) - 1.f);
        acc.w += (ew > 0.f) ? ew : (expf(ew) - 1.f);
    }
    const float q = 1.f / (float)H_;
    float4 r = {acc.x * q, acc.y * q, acc.z * q, acc.w * q};
    reinterpret_cast<float4*>(out)[i] = r;
}

extern "C" void kernel_launch(void* const* d_in, const int* in_sizes, int n_in,
                              void* d_out, int out_size, void* d_ws, size_t ws_size,
                              hipStream_t stream) {
    const float* x = (const float*)d_in[0];   // (T, N, F)
    const float* W = (const float*)d_in[1];   // (H, F, F)
    float* out = (float*)d_out;               // (N, F)

    // ws layout: th_hi 16MB | th_hiT 16MB | s_part 32MB (64MB)
    const size_t TH = (size_t)H_ * T_ * N_ * F_;        // 8,388,608
    ushort_t* th_hi  = (ushort_t*)d_ws;
    ushort_t* th_hiT = th_hi + TH;
    float* s_part = (float*)(th_hiT + TH);

    k_th<<<H_ * T_ * (N_ / 64), 256, 0, stream>>>(x, W, th_hi, th_hiT);
    k_attn<<<512, 256, 0, stream>>>(th_hi, th_hiT, s_part);
    k_out<<<(N_ * F_ / 4 + 255) / 256, 256, 0, stream>>>(s_part, out);
}